// Round 12
// baseline (84.165 us; speedup 1.0000x reference)
//
#include <hip/hip_runtime.h>
#include <hip/hip_bf16.h>

typedef __attribute__((ext_vector_type(8))) short short8;
typedef __attribute__((ext_vector_type(4))) float f32x4;

#define KB 64            // K-chunks; block covers 4 hi = 1024 rules
#define HPB 4            // hi per block (256/KB)
#define SPT 64           // samples per block (4 MFMA sub-tiles of 16)

__device__ __forceinline__ ushort f2bf(float f) {            // RNE via v_cvt
    __hip_bfloat16 h = __float2bfloat16(f);
    return *reinterpret_cast<ushort*>(&h);
}
__device__ __forceinline__ unsigned pk2(float a, float b) {
    return (unsigned)f2bf(a) | ((unsigned)f2bf(b) << 16);
}

// Block = (sample-tile of 64) x (k-chunk of 1024 rules = 4 hi).
// k-split: wave wv owns K-steps {2wv, 2wv+1} of every hi -> its B-rows are
// local rows [64wv, 64wv+64) of each staged 256-row chunk, staged into a
// PRIVATE LDS region (lane l stages local row 64wv+l: one 32B-contiguous W
// row + b). Zero barriers in the hot loop; four 16-sample MFMA sub-tiles
// share each staged B fragment (4x arithmetic intensity vs 16-sample blocks).
// Cross-wave fold via LDS float atomics into red[64][12] (zero-initialized in
// prologue) -> one barrier before the epilogue; block atomically adds its
// chunk's contribution into out (out pre-zeroed by a 4KB memset).
__global__ __launch_bounds__(256) void fz_main(
    const float* __restrict__ x, const float* __restrict__ center,
    const float* __restrict__ sigma, const float* __restrict__ W,
    const float* __restrict__ b, float* __restrict__ out, int N)
{
    __shared__ float  mgs[SPT][33];     // memberships (padded rows)
    __shared__ float  pr[SPT][20]  __attribute__((aligned(16))); // d6,d7 pair products
    __shared__ float  phs[HPB][68] __attribute__((aligned(16))); // ph[hi][sample]
    __shared__ float  red[SPT][12];     // cross-wave fold (LDS atomics)
    __shared__ ushort wstg[4][2][8][17][8] __attribute__((aligned(16)));
    // wstg[wv][buf][rb][col][r8]: element (local row,col) at [r>>3][c][r&7].
    // col dim padded to 17 -> rb stride 136 ushorts: per-lane ds_write_b16
    // spread over all 32 banks; reads are 16B-aligned ds_read_b128.

    const int t = threadIdx.x;
    const int tile = blockIdx.x >> 6;   // KB==64
    const int kb = blockIdx.x & (KB - 1);

    #pragma unroll
    for (int v = 0; v < 8; ++v) {       // 2048 mg values, 8/thread
        int id = t + v * 256;
        int s = id >> 5, i = id & 31, m = i >> 2;
        float xv = x[(size_t)(tile * SPT + s) * 8 + m];
        float d = xv - center[i];
        float sg = sigma[i];
        mgs[s][i] = __expf(-d * d * 0.5f * sg * sg);
    }
    #pragma unroll
    for (int v = 0; v < 3; ++v) {       // zero red[64][12], 3/thread
        int id = t + v * 256;
        if (id < SPT * 12) (&red[0][0])[id] = 0.f;
    }
    __syncthreads();
    #pragma unroll
    for (int v = 0; v < 4; ++v) {       // pair table pr[s][4*d6+d7], 4/thread
        int s = (t >> 4) + v * 16, a = t & 15;
        pr[s][a] = mgs[s][24 + (a >> 2)] * mgs[s][28 + (a & 3)];
    }
    {   // ph table [hi][sample]: one value per thread (fp32 exact)
        int hil = t >> 6, s = t & 63;
        int hi = kb * HPB + hil;
        phs[hil][s] = mgs[s][hi >> 6] * mgs[s][4 + ((hi >> 4) & 3)]
                    * mgs[s][8 + ((hi >> 2) & 3)] * mgs[s][12 + (hi & 3)];
    }
    __syncthreads();

    const int wv = t >> 6, lane = t & 63;
    const int c = lane & 15, kb4 = lane >> 4;

    // A-frags in registers: A[st][q] = pl(sample st*16+(lane&15), k-step 2wv+q)
    short8 A[4][2];
    #pragma unroll
    for (int st = 0; st < 4; ++st) {
        const int s_a = st * 16 + (lane & 15);
        #pragma unroll
        for (int q = 0; q < 2; ++q) {
            const int ls = 2 * wv + q;
            const int L0 = ls * 32 + kb4 * 8;        // lo = L0 + j, j = 0..7
            const float pq = mgs[s_a][16 + (L0 >> 6)] * mgs[s_a][20 + ((L0 >> 4) & 3)];
            const int b7 = L0 & 8;
            const float4 r0 = *reinterpret_cast<const float4*>(&pr[s_a][b7]);
            const float4 r1 = *reinterpret_cast<const float4*>(&pr[s_a][b7 + 4]);
            unsigned Pk[4] = { pk2(pq * r0.x, pq * r0.y), pk2(pq * r0.z, pq * r0.w),
                               pk2(pq * r1.x, pq * r1.y), pk2(pq * r1.z, pq * r1.w) };
            A[st][q] = *reinterpret_cast<short8*>(&Pk[0]);
        }
    }

    // wave-private staging: lane l owns global rule row kb*1024 + hil*256 + 64wv + l
    const float* wrow = W + ((size_t)kb * 1024 + 64 * wv + lane) * 8;
    const float* brow = b + kb * 1024 + 64 * wv + lane;
    ushort* rg = &wstg[wv][0][0][0][0];          // 2 bufs x 1088 ushorts

    auto sload = [&](int hil, float4& wa, float4& wb, float& bv) {
        wa = *reinterpret_cast<const float4*>(wrow + hil * 2048);
        wb = *reinterpret_cast<const float4*>(wrow + hil * 2048 + 4);
        bv = brow[hil * 256];
    };
    auto swrite = [&](int buf, const float4& wa, const float4& wb, float bv) {
        ushort* p = rg + buf * 1088 + (lane >> 3) * 136 + (lane & 7);
        p[0]  = f2bf(wa.x); p[8]  = f2bf(wa.y); p[16] = f2bf(wa.z); p[24] = f2bf(wa.w);
        p[32] = f2bf(wb.x); p[40] = f2bf(wb.y); p[48] = f2bf(wb.z); p[56] = f2bf(wb.w);
        p[64] = f2bf(bv);                        // b -> col 8
    };

    float4 wa, wb2; float bv;
    sload(0, wa, wb2, bv);
    swrite(0, wa, wb2, bv);

    f32x4 master[4] = {{0.f,0.f,0.f,0.f},{0.f,0.f,0.f,0.f},
                       {0.f,0.f,0.f,0.f},{0.f,0.f,0.f,0.f}};
    #pragma unroll
    for (int hil = 0; hil < HPB; ++hil) {        // ZERO barriers in this loop
        const int buf = hil & 1;
        if (hil + 1 < HPB) sload(hil + 1, wa, wb2, bv);  // VMEM in flight
        const ushort* q = rg + buf * 1088 + kb4 * 136 + c * 8;
        short8 B0 = *reinterpret_cast<const short8*>(q);            // k-step 2wv
        short8 B1 = *reinterpret_cast<const short8*>(q + 4 * 136);  // k-step 2wv+1
        #pragma unroll
        for (int st = 0; st < 4; ++st) {
            f32x4 d = {0.f, 0.f, 0.f, 0.f};
            d = __builtin_amdgcn_mfma_f32_16x16x32_bf16(A[st][0], B0, d, 0, 0, 0);
            d = __builtin_amdgcn_mfma_f32_16x16x32_bf16(A[st][1], B1, d, 0, 0, 0);
            const float4 phv =
                *reinterpret_cast<const float4*>(&phs[hil][st * 16 + kb4 * 4]);
            master[st][0] += phv.x * d[0]; master[st][1] += phv.y * d[1];
            master[st][2] += phv.z * d[2]; master[st][3] += phv.w * d[3];
        }
        if (hil + 1 < HPB) swrite(buf ^ 1, wa, wb2, bv); // other buffer: no hazard
    }

    // fold the 4 waves (disjoint k-slices) via LDS float atomics (<=4-way)
    if (c < 9) {
        #pragma unroll
        for (int st = 0; st < 4; ++st)
            #pragma unroll
            for (int r = 0; r < 4; ++r)
                atomicAdd(&red[st * 16 + kb4 * 4 + r][c], master[st][r]);
    }
    __syncthreads();
    if (t < SPT) {                      // finish: denom from mgs (exact), fused add
        const int s = t;
        float denom = 1.f;
        #pragma unroll
        for (int m = 0; m < 8; ++m)
            denom *= (mgs[s][4 * m] + mgs[s][4 * m + 1] +
                      mgs[s][4 * m + 2] + mgs[s][4 * m + 3]);
        float num = red[s][8];
        #pragma unroll
        for (int m = 0; m < 8; ++m)
            num += x[(size_t)(tile * SPT + s) * 8 + m] * red[s][m];
        atomicAdd(&out[tile * SPT + s], num / denom);
    }
}

extern "C" void kernel_launch(void* const* d_in, const int* in_sizes, int n_in,
                              void* d_out, int out_size, void* d_ws, size_t ws_size,
                              hipStream_t stream)
{
    const float* x      = (const float*)d_in[0];
    const float* center = (const float*)d_in[1];
    const float* sigma  = (const float*)d_in[2];
    const float* W      = (const float*)d_in[3];
    const float* b      = (const float*)d_in[4];
    float* out = (float*)d_out;
    const int N = in_sizes[0] / 8;          // 1024

    hipMemsetAsync(out, 0, (size_t)out_size * sizeof(float), stream);
    fz_main<<<(N / SPT) * KB, 256, 0, stream>>>(x, center, sigma, W, b, out, N);
}